// Round 13
// baseline (57.387 us; speedup 1.0000x reference)
//
#include <hip/hip_runtime.h>
#include <hip/hip_bf16.h>
#include <cstdint>
#include <cstddef>

typedef __attribute__((ext_vector_type(8))) short bf16x8;
typedef __attribute__((ext_vector_type(4))) float f32x4;
typedef __attribute__((ext_vector_type(4))) unsigned int u32x4;

#define T_DIM 2048
#define C_DIM 1024
#define B_DIM 8
#define NEG_BIG (-3.0e38f)
#define QSCALE 0.18033688011112042f   // (1/8) * log2(e): softmax in exp2 domain

__device__ __forceinline__ unsigned short f2bf(float f) {
  union { __hip_bfloat16 h; unsigned short u; } cv;
  cv.h = __float2bfloat16(f);
  return cv.u;
}
__device__ __forceinline__ f32x4 mfma16(bf16x8 a, bf16x8 b, f32x4 c) {
  return __builtin_amdgcn_mfma_f32_16x16x32_bf16(a, b, c, 0, 0, 0);
}

// ---------------------------------------------------------------------------
// prep_w: W [1024][64] f32 -> Wt [3][64][1024] bf16 (transposed; Wq scaled by
// (1/8)*log2e so softmax runs in exp2 domain).
// ---------------------------------------------------------------------------
__global__ __launch_bounds__(256) void prep_w(
    const float* __restrict__ Wq, const float* __restrict__ Wk,
    const float* __restrict__ Wv, unsigned short* __restrict__ Wt)
{
  const int mtx = blockIdx.x >> 4;
  const int k0  = (blockIdx.x & 15) * 64;
  const float* W = (mtx == 0) ? Wq : ((mtx == 1) ? Wk : Wv);
  const float scale = (mtx == 0) ? QSCALE : 1.0f;
  __shared__ float Ws[64][65];
  const int t = threadIdx.x;
#pragma unroll
  for (int j = 0; j < 4; ++j) {
    int r = (t >> 4) + 16 * j;
    int c = (t & 15) * 4;
    union { float4 f4; float f[4]; } uv;
    uv.f4 = *(const float4*)&W[(size_t)(k0 + r) * 64 + c];
#pragma unroll
    for (int jj = 0; jj < 4; ++jj) Ws[c + jj][r] = uv.f[jj] * scale;
  }
  __syncthreads();
#pragma unroll
  for (int q = 0; q < 2; ++q) {
    int g_ = t + 256 * q;
    int d  = g_ >> 3;
    int ko = (g_ & 7) * 8;
    union { unsigned short u[8]; u32x4 v; } pk;
#pragma unroll
    for (int jj = 0; jj < 8; ++jj) pk.u[jj] = f2bf(Ws[d][ko + jj]);
    *(u32x4*)&Wt[((size_t)mtx * 64 + d) * C_DIM + k0 + ko] = pk.v;
  }
}

// ---------------------------------------------------------------------------
// qkv_proj_mfma: round-12 pipelined version (512 x 32 rows). Unchanged except
// the Q-bias scale constant (exp2 domain).
// ---------------------------------------------------------------------------
__global__ __launch_bounds__(256) void qkv_proj_mfma(
    const float* __restrict__ x,
    const unsigned short* __restrict__ Wt,
    const float* __restrict__ bq, const float* __restrict__ bk, const float* __restrict__ bv,
    unsigned short* __restrict__ Qb, unsigned short* __restrict__ Kb,
    unsigned short* __restrict__ VTb)
{
  __shared__ __align__(16) short Xs[2][32 * 64];
  __shared__ __align__(16) short Wsb[2][3 * 64 * 64];
  __shared__ __align__(16) unsigned short VTs[64 * 40];

  const int tid = threadIdx.x;
  const int wv = tid >> 6, lane = tid & 63, g = lane >> 4, ln15 = lane & 15;
  const size_t m0 = (size_t)blockIdx.x * 32;

  f32x4 acc[2][3];
#pragma unroll
  for (int mt = 0; mt < 2; ++mt)
#pragma unroll
    for (int j = 0; j < 3; ++j) acc[mt][j] = (f32x4){0.f, 0.f, 0.f, 0.f};

  float4 xA[2], xB[2];
  u32x4 wr[6];

  auto issueX = [&](float4 (&xr)[2], int kt) {
    if (kt >= 16) return;
#pragma unroll
    for (int q = 0; q < 2; ++q) {
      int g_ = tid + 256 * q;
      int r = g_ >> 4, c4 = (g_ & 15) * 4;
      xr[q] = *(const float4*)&x[(m0 + r) * C_DIM + kt * 64 + c4];
    }
  };
  auto issueW = [&](int kt) {
    if (kt >= 16) return;
#pragma unroll
    for (int mt = 0; mt < 3; ++mt)
#pragma unroll
      for (int q = 0; q < 2; ++q) {
        int g_ = tid + 256 * q;
        int d = g_ >> 3, ko = (g_ & 7) * 8;
        wr[mt * 2 + q] = *(const u32x4*)&Wt[((size_t)mt * 64 + d) * C_DIM + kt * 64 + ko];
      }
  };
  auto writeXb = [&](int nb, const float4 (&xr)[2]) {
#pragma unroll
    for (int q = 0; q < 2; ++q) {
      int g_ = tid + 256 * q;
      int r = g_ >> 4, c4 = (g_ & 15) * 4;
      const float* f = (const float*)&xr[q];
      union { unsigned short u[4]; unsigned long long ll; } pk;
#pragma unroll
      for (int jj = 0; jj < 4; ++jj) pk.u[jj] = f2bf(f[jj]);
      *(unsigned long long*)((char*)Xs[nb] + r * 128 + ((c4 * 2) ^ ((r & 7) << 4))) = pk.ll;
    }
  };
  auto writeWb = [&](int nb) {
#pragma unroll
    for (int mt = 0; mt < 3; ++mt)
#pragma unroll
      for (int q = 0; q < 2; ++q) {
        int g_ = tid + 256 * q;
        int d = g_ >> 3, ko = (g_ & 7) * 8;
        *(u32x4*)((char*)Wsb[nb] + mt * 8192 + d * 128 + ((ko * 2) ^ ((d & 7) << 4))) = wr[mt * 2 + q];
      }
  };
  auto compute = [&](int nb) {
#pragma unroll
    for (int kc = 0; kc < 2; ++kc) {
      bf16x8 a[2];
#pragma unroll
      for (int mt = 0; mt < 2; ++mt) {
        int xr = mt * 16 + ln15;
        a[mt] = *(const bf16x8*)((const char*)Xs[nb] + xr * 128 + ((kc * 64 + g * 16) ^ ((xr & 7) << 4)));
      }
#pragma unroll
      for (int j = 0; j < 3; ++j) {
        int ntg = wv * 3 + j;
        int mtx = ntg >> 2, nc = (ntg & 3) * 16;
        int wrow = nc + ln15;
        bf16x8 bb = *(const bf16x8*)((const char*)Wsb[nb] + mtx * 8192 + wrow * 128 + ((kc * 64 + g * 16) ^ ((wrow & 7) << 4)));
#pragma unroll
        for (int mt = 0; mt < 2; ++mt)
          acc[mt][j] = mfma16(a[mt], bb, acc[mt][j]);
      }
    }
  };

  issueX(xA, 0); issueW(0);
  writeXb(0, xA); writeWb(0);
  issueX(xB, 1);
  __syncthreads();

  for (int kt = 0; kt < 16; kt += 2) {
    issueW(kt + 1);
    issueX(xA, kt + 2);
    compute(0);
    if (kt + 1 < 16) { writeXb(1, xB); writeWb(1); }
    __syncthreads();
    if (kt + 1 < 16) {
      issueW(kt + 2);
      issueX(xB, kt + 3);
      compute(1);
      if (kt + 2 < 16) { writeXb(0, xA); writeWb(0); }
      __syncthreads();
    }
  }

#pragma unroll
  for (int j = 0; j < 3; ++j) {
    int ntg = wv * 3 + j;
    int mtx = ntg >> 2, nc = (ntg & 3) * 16;
    if (mtx < 2) {
      const float* bias = (mtx == 0) ? bq : bk;
      unsigned short* Out = (mtx == 0) ? Qb : Kb;
      float bvv = bias[nc + ln15] * ((mtx == 0) ? QSCALE : 1.0f);
#pragma unroll
      for (int mt = 0; mt < 2; ++mt)
#pragma unroll
        for (int i = 0; i < 4; ++i)
          Out[(m0 + mt * 16 + 4 * g + i) * 64 + nc + ln15] = f2bf(acc[mt][j][i] + bvv);
    } else {
      float bvv = bv[nc + ln15];
#pragma unroll
      for (int mt = 0; mt < 2; ++mt)
#pragma unroll
        for (int i = 0; i < 4; ++i)
          VTs[(nc + ln15) * 40 + mt * 16 + 4 * g + i] = f2bf(acc[mt][j][i] + bvv);
    }
  }
  __syncthreads();
  {
    int d = tid >> 2, t8 = (tid & 3) * 8;
    u32x4 v0 = *(const u32x4*)&VTs[d * 40 + t8];
    size_t b = m0 >> 11, tloc = m0 & 2047;
    *(u32x4*)&VTb[(b * 64 + d) * T_DIM + tloc + t8] = v0;
  }
}

// ---------------------------------------------------------------------------
// attn_flash: swapped-operand flash attention, 2-WAY CROSS-BLOCK KV SPLIT.
// Grid 1024 = 64 qt x 8 b x 2 halves (LPT). Each block runs the round-11
// 4-wave structure on its kv sub-range and writes an UNNORMALIZED partial
// (Z, m, l): half 0 -> out, half 1 -> Zp. exp2-domain softmax (scores carry
// log2e). P-slabs and merge-slabs alias one LDS union (barrier before reuse).
// ---------------------------------------------------------------------------
__global__ __launch_bounds__(256) void attn_flash(
    const unsigned short* __restrict__ Qb,   // [B*T][64] (pre-scaled QSCALE)
    const unsigned short* __restrict__ Kb,   // [B*T][64]
    const unsigned short* __restrict__ VTb,  // [B][64][T]
    float* __restrict__ out,                 // partial half 0 (unnormalized Z)
    float* __restrict__ Zp,                  // partial half 1
    float* __restrict__ MlG)                 // [2][16384][2] (m,l)
{
  __shared__ __align__(16) char Usm[26112]; // union: Ps (16KB) / Zs (25.5KB)
  __shared__ float Ml[3][2][16][2];

  const int tid  = threadIdx.x;
  const int wv   = tid >> 6;
  const int lane = tid & 63;
  const int g    = lane >> 4;
  const int ln15 = lane & 15;

  const int bx  = blockIdx.x;
  const int qt  = 63 - (bx >> 4);           // 16 blocks per qt (8 b x 2 h), LPT
  const int sub = bx & 15;
  const int b   = sub & 7;
  const int h   = sub >> 3;
  const int r0  = qt * 32;
  const int ntiles = (qt >> 1) + 1;
  const int nt2 = (ntiles + 1) >> 1;        // half 0: [0,nt2) (never empty)
  const int lo  = h ? nt2 : 0;
  const int hi  = h ? ntiles : nt2;

  const size_t bT = (size_t)b * T_DIM;

  bf16x8 qa[2][2];
#pragma unroll
  for (int mt = 0; mt < 2; ++mt) {
    const unsigned short* qp = Qb + (bT + r0 + mt * 16 + ln15) * 64 + g * 8;
    qa[mt][0] = *(const bf16x8*)qp;
    qa[mt][1] = *(const bf16x8*)(qp + 32);
  }

  f32x4 acc[2][4];
#pragma unroll
  for (int mt = 0; mt < 2; ++mt)
#pragma unroll
    for (int dt = 0; dt < 4; ++dt) acc[mt][dt] = (f32x4){0.f, 0.f, 0.f, 0.f};
  float m_[2], l_[2];
#pragma unroll
  for (int mt = 0; mt < 2; ++mt) { m_[mt] = NEG_BIG; l_[mt] = 0.f; }

  char* myP = Usm + wv * 4096;

  for (int it = lo + wv; it < hi; it += 4) {
    const int s0 = it * 64;
    bf16x8 kf[4][2];
#pragma unroll
    for (int nt = 0; nt < 4; ++nt) {
      const unsigned short* kp = Kb + (bT + s0 + nt * 16 + ln15) * 64 + g * 8;
      kf[nt][0] = *(const bf16x8*)kp;
      kf[nt][1] = *(const bf16x8*)(kp + 32);
    }
    bf16x8 vf[4][2];
#pragma unroll
    for (int dt = 0; dt < 4; ++dt) {
      const unsigned short* vp = VTb + ((size_t)b * 64 + dt * 16 + ln15) * T_DIM + s0 + g * 8;
      vf[dt][0] = *(const bf16x8*)vp;
      vf[dt][1] = *(const bf16x8*)(vp + 32);
    }
    f32x4 st[2][4];
#pragma unroll
    for (int mt = 0; mt < 2; ++mt)
#pragma unroll
      for (int nt = 0; nt < 4; ++nt) {
        f32x4 a = (f32x4){0.f, 0.f, 0.f, 0.f};
        a = mfma16(kf[nt][0], qa[mt][0], a);
        a = mfma16(kf[nt][1], qa[mt][1], a);
        st[mt][nt] = a;
      }
    if (s0 + 63 > r0) {
#pragma unroll
      for (int mt = 0; mt < 2; ++mt) {
        const int qg = r0 + mt * 16 + ln15;
#pragma unroll
        for (int nt = 0; nt < 4; ++nt) {
          const int kvb = s0 + nt * 16 + 4 * g;
#pragma unroll
          for (int i = 0; i < 4; ++i)
            if (kvb + i > qg) st[mt][nt][i] = NEG_BIG;
        }
      }
    }
#pragma unroll
    for (int mt = 0; mt < 2; ++mt) {
      f32x4 t4;
#pragma unroll
      for (int i = 0; i < 4; ++i)
        t4[i] = fmaxf(fmaxf(st[mt][0][i], st[mt][1][i]), fmaxf(st[mt][2][i], st[mt][3][i]));
      float mx = fmaxf(fmaxf(t4[0], t4[1]), fmaxf(t4[2], t4[3]));
      mx = fmaxf(mx, __shfl_xor(mx, 16));
      mx = fmaxf(mx, __shfl_xor(mx, 32));
      const float mn = fmaxf(m_[mt], mx);
      const float corr = exp2f(m_[mt] - mn);
      m_[mt] = mn;
#pragma unroll
      for (int nt = 0; nt < 4; ++nt)
#pragma unroll
        for (int i = 0; i < 4; ++i)
          st[mt][nt][i] = exp2f(st[mt][nt][i] - mn);
      float ps = 0.f;
#pragma unroll
      for (int nt = 0; nt < 4; ++nt)
        ps += (st[mt][nt][0] + st[mt][nt][1]) + (st[mt][nt][2] + st[mt][nt][3]);
      ps += __shfl_xor(ps, 16);
      ps += __shfl_xor(ps, 32);
      l_[mt] = l_[mt] * corr + ps;
#pragma unroll
      for (int dt = 0; dt < 4; ++dt)
#pragma unroll
        for (int i = 0; i < 4; ++i)
          acc[mt][dt][i] *= corr;
#pragma unroll
      for (int nt = 0; nt < 4; ++nt) {
        unsigned int lo_ = (unsigned int)f2bf(st[mt][nt][0]) | ((unsigned int)f2bf(st[mt][nt][1]) << 16);
        unsigned int hi_ = (unsigned int)f2bf(st[mt][nt][2]) | ((unsigned int)f2bf(st[mt][nt][3]) << 16);
        *(unsigned long long*)(myP + mt * 2048 + ln15 * 128 +
                               ((nt * 32 + g * 8) ^ ((ln15 & 7) << 4))) =
            ((unsigned long long)hi_ << 32) | lo_;
      }
    }
    bf16x8 pb[2][2];
#pragma unroll
    for (int mt = 0; mt < 2; ++mt)
#pragma unroll
      for (int kc = 0; kc < 2; ++kc)
        pb[mt][kc] = *(const bf16x8*)(myP + mt * 2048 + ln15 * 128 +
                                      ((kc * 64 + g * 16) ^ ((ln15 & 7) << 4)));
#pragma unroll
    for (int mt = 0; mt < 2; ++mt)
#pragma unroll
      for (int dt = 0; dt < 4; ++dt) {
        acc[mt][dt] = mfma16(vf[dt][0], pb[mt][0], acc[mt][dt]);
        acc[mt][dt] = mfma16(vf[dt][1], pb[mt][1], acc[mt][dt]);
      }
  }

  __syncthreads();                  // all waves done with Ps before Zs reuse
  float* Zsf = (float*)Usm;         // [3][2][16*68]
  if (wv > 0) {
#pragma unroll
    for (int mt = 0; mt < 2; ++mt) {
#pragma unroll
      for (int dt = 0; dt < 4; ++dt)
        *(f32x4*)&Zsf[((wv - 1) * 2 + mt) * 1088 + ln15 * 68 + dt * 16 + 4 * g] = acc[mt][dt];
      if (g == 0) {
        Ml[wv - 1][mt][ln15][0] = m_[mt];
        Ml[wv - 1][mt][ln15][1] = l_[mt];
      }
    }
  }
  __syncthreads();
  if (wv == 0) {
    float* Zdst = h ? Zp : out;
#pragma unroll
    for (int mt = 0; mt < 2; ++mt) {
      float mm = m_[mt];
#pragma unroll
      for (int w = 0; w < 3; ++w) mm = fmaxf(mm, Ml[w][mt][ln15][0]);
      const float e0 = exp2f(m_[mt] - mm);
      float lsum = l_[mt] * e0;
      float ew[3];
#pragma unroll
      for (int w = 0; w < 3; ++w) {
        ew[w] = exp2f(Ml[w][mt][ln15][0] - mm);
        lsum += Ml[w][mt][ln15][1] * ew[w];
      }
      const size_t row = bT + r0 + mt * 16 + ln15;
      float* ob = Zdst + row * 64;
#pragma unroll
      for (int dt = 0; dt < 4; ++dt) {
        f32x4 z;
#pragma unroll
        for (int i = 0; i < 4; ++i) {
          float zz = acc[mt][dt][i] * e0;
#pragma unroll
          for (int w = 0; w < 3; ++w)
            zz += Zsf[(w * 2 + mt) * 1088 + ln15 * 68 + dt * 16 + 4 * g + i] * ew[w];
          z[i] = zz;                 // unnormalized partial
        }
        *(f32x4*)&ob[dt * 16 + 4 * g] = z;
      }
      if (g == 0) {
        MlG[((size_t)h * 16384 + row) * 2 + 0] = mm;
        MlG[((size_t)h * 16384 + row) * 2 + 1] = lsum;
      }
    }
  }
}

// ---------------------------------------------------------------------------
// merge_halves: out = (Z0*e0 + Z1*e1) / (l0*e0 + l1*e1) per q-row.
// Grid 4096 x 256: 4 rows/block, lane = d. L2-resident (~12 MB).
// ---------------------------------------------------------------------------
__global__ __launch_bounds__(256) void merge_halves(
    float* __restrict__ out, const float* __restrict__ Zp,
    const float* __restrict__ MlG)
{
  const int row  = blockIdx.x * 4 + (threadIdx.x >> 6);
  const int lane = threadIdx.x & 63;
  const float mA = MlG[(size_t)row * 2 + 0];
  const float lA = MlG[(size_t)row * 2 + 1];
  const float mB = MlG[((size_t)16384 + row) * 2 + 0];
  const float lB = MlG[((size_t)16384 + row) * 2 + 1];
  const float mm = fmaxf(mA, mB);
  const float eA = exp2f(mA - mm), eB = exp2f(mB - mm);
  const float inv = 1.0f / (lA * eA + lB * eB);
  const size_t idx = (size_t)row * 64 + lane;
  out[idx] = (out[idx] * eA + Zp[idx] * eB) * inv;
}

// ---------------------------------------------------------------------------
extern "C" void kernel_launch(void* const* d_in, const int* in_sizes, int n_in,
                              void* d_out, int out_size, void* d_ws, size_t ws_size,
                              hipStream_t stream)
{
  const float* x  = (const float*)d_in[0];
  const float* Wq = (const float*)d_in[1];
  const float* bq = (const float*)d_in[2];
  const float* Wk = (const float*)d_in[3];
  const float* bk = (const float*)d_in[4];
  const float* Wv = (const float*)d_in[5];
  const float* bv = (const float*)d_in[6];
  float* out = (float*)d_out;

  char* ws = (char*)d_ws;
  unsigned short* Wt  = (unsigned short*)(ws);                        // 384 KB
  unsigned short* Qb  = (unsigned short*)(ws + (1u << 19));           // 2 MB
  unsigned short* Kb  = (unsigned short*)(ws + (1u << 19) + (1u << 21));
  unsigned short* VTb = (unsigned short*)(ws + (1u << 19) + (2u << 21));
  float*          Zp  = (float*)(ws + (1u << 19) + (3u << 21));       // 4 MB
  float*          MlG = (float*)(ws + (1u << 19) + (3u << 21) + (1u << 22)); // 256 KB

  prep_w<<<48, 256, 0, stream>>>(Wq, Wk, Wv, Wt);
  qkv_proj_mfma<<<512, 256, 0, stream>>>(x, Wt, bq, bk, bv, Qb, Kb, VTb);
  attn_flash<<<1024, 256, 0, stream>>>(Qb, Kb, VTb, out, Zp, MlG);
  merge_halves<<<4096, 256, 0, stream>>>(out, Zp, MlG);
}

// Round 14
// 54.897 us; speedup vs baseline: 1.0454x; 1.0454x over previous
//
#include <hip/hip_runtime.h>
#include <hip/hip_bf16.h>
#include <cstdint>
#include <cstddef>

typedef __attribute__((ext_vector_type(8))) short bf16x8;
typedef __attribute__((ext_vector_type(4))) float f32x4;
typedef __attribute__((ext_vector_type(4))) unsigned int u32x4;

#define T_DIM 2048
#define C_DIM 1024
#define B_DIM 8
#define NEG_BIG (-3.0e38f)
#define QSCALE 0.18033688011112042f   // (1/8) * log2(e): softmax in exp2 domain

__device__ __forceinline__ unsigned short f2bf(float f) {
  union { __hip_bfloat16 h; unsigned short u; } cv;
  cv.h = __float2bfloat16(f);
  return cv.u;
}
__device__ __forceinline__ f32x4 mfma16(bf16x8 a, bf16x8 b, f32x4 c) {
  return __builtin_amdgcn_mfma_f32_16x16x32_bf16(a, b, c, 0, 0, 0);
}

// ---------------------------------------------------------------------------
// prep_w: W [1024][64] f32 -> Wt [3][64][1024] bf16 (transposed; Wq scaled by
// (1/8)*log2e so softmax runs in exp2 domain). Unchanged from round 13.
// ---------------------------------------------------------------------------
__global__ __launch_bounds__(256) void prep_w(
    const float* __restrict__ Wq, const float* __restrict__ Wk,
    const float* __restrict__ Wv, unsigned short* __restrict__ Wt)
{
  const int mtx = blockIdx.x >> 4;
  const int k0  = (blockIdx.x & 15) * 64;
  const float* W = (mtx == 0) ? Wq : ((mtx == 1) ? Wk : Wv);
  const float scale = (mtx == 0) ? QSCALE : 1.0f;
  __shared__ float Ws[64][65];
  const int t = threadIdx.x;
#pragma unroll
  for (int j = 0; j < 4; ++j) {
    int r = (t >> 4) + 16 * j;
    int c = (t & 15) * 4;
    union { float4 f4; float f[4]; } uv;
    uv.f4 = *(const float4*)&W[(size_t)(k0 + r) * 64 + c];
#pragma unroll
    for (int jj = 0; jj < 4; ++jj) Ws[c + jj][r] = uv.f[jj] * scale;
  }
  __syncthreads();
#pragma unroll
  for (int q = 0; q < 2; ++q) {
    int g_ = t + 256 * q;
    int d  = g_ >> 3;
    int ko = (g_ & 7) * 8;
    union { unsigned short u[8]; u32x4 v; } pk;
#pragma unroll
    for (int jj = 0; jj < 8; ++jj) pk.u[jj] = f2bf(Ws[d][ko + jj]);
    *(u32x4*)&Wt[((size_t)mtx * 64 + d) * C_DIM + k0 + ko] = pk.v;
  }
}

// ---------------------------------------------------------------------------
// qkv_proj_mfma: round-12/13 pipelined version (512 x 32 rows). Unchanged.
// ---------------------------------------------------------------------------
__global__ __launch_bounds__(256) void qkv_proj_mfma(
    const float* __restrict__ x,
    const unsigned short* __restrict__ Wt,
    const float* __restrict__ bq, const float* __restrict__ bk, const float* __restrict__ bv,
    unsigned short* __restrict__ Qb, unsigned short* __restrict__ Kb,
    unsigned short* __restrict__ VTb)
{
  __shared__ __align__(16) short Xs[2][32 * 64];
  __shared__ __align__(16) short Wsb[2][3 * 64 * 64];
  __shared__ __align__(16) unsigned short VTs[64 * 40];

  const int tid = threadIdx.x;
  const int wv = tid >> 6, lane = tid & 63, g = lane >> 4, ln15 = lane & 15;
  const size_t m0 = (size_t)blockIdx.x * 32;

  f32x4 acc[2][3];
#pragma unroll
  for (int mt = 0; mt < 2; ++mt)
#pragma unroll
    for (int j = 0; j < 3; ++j) acc[mt][j] = (f32x4){0.f, 0.f, 0.f, 0.f};

  float4 xA[2], xB[2];
  u32x4 wr[6];

  auto issueX = [&](float4 (&xr)[2], int kt) {
    if (kt >= 16) return;
#pragma unroll
    for (int q = 0; q < 2; ++q) {
      int g_ = tid + 256 * q;
      int r = g_ >> 4, c4 = (g_ & 15) * 4;
      xr[q] = *(const float4*)&x[(m0 + r) * C_DIM + kt * 64 + c4];
    }
  };
  auto issueW = [&](int kt) {
    if (kt >= 16) return;
#pragma unroll
    for (int mt = 0; mt < 3; ++mt)
#pragma unroll
      for (int q = 0; q < 2; ++q) {
        int g_ = tid + 256 * q;
        int d = g_ >> 3, ko = (g_ & 7) * 8;
        wr[mt * 2 + q] = *(const u32x4*)&Wt[((size_t)mt * 64 + d) * C_DIM + kt * 64 + ko];
      }
  };
  auto writeXb = [&](int nb, const float4 (&xr)[2]) {
#pragma unroll
    for (int q = 0; q < 2; ++q) {
      int g_ = tid + 256 * q;
      int r = g_ >> 4, c4 = (g_ & 15) * 4;
      const float* f = (const float*)&xr[q];
      union { unsigned short u[4]; unsigned long long ll; } pk;
#pragma unroll
      for (int jj = 0; jj < 4; ++jj) pk.u[jj] = f2bf(f[jj]);
      *(unsigned long long*)((char*)Xs[nb] + r * 128 + ((c4 * 2) ^ ((r & 7) << 4))) = pk.ll;
    }
  };
  auto writeWb = [&](int nb) {
#pragma unroll
    for (int mt = 0; mt < 3; ++mt)
#pragma unroll
      for (int q = 0; q < 2; ++q) {
        int g_ = tid + 256 * q;
        int d = g_ >> 3, ko = (g_ & 7) * 8;
        *(u32x4*)((char*)Wsb[nb] + mt * 8192 + d * 128 + ((ko * 2) ^ ((d & 7) << 4))) = wr[mt * 2 + q];
      }
  };
  auto compute = [&](int nb) {
#pragma unroll
    for (int kc = 0; kc < 2; ++kc) {
      bf16x8 a[2];
#pragma unroll
      for (int mt = 0; mt < 2; ++mt) {
        int xr = mt * 16 + ln15;
        a[mt] = *(const bf16x8*)((const char*)Xs[nb] + xr * 128 + ((kc * 64 + g * 16) ^ ((xr & 7) << 4)));
      }
#pragma unroll
      for (int j = 0; j < 3; ++j) {
        int ntg = wv * 3 + j;
        int mtx = ntg >> 2, nc = (ntg & 3) * 16;
        int wrow = nc + ln15;
        bf16x8 bb = *(const bf16x8*)((const char*)Wsb[nb] + mtx * 8192 + wrow * 128 + ((kc * 64 + g * 16) ^ ((wrow & 7) << 4)));
#pragma unroll
        for (int mt = 0; mt < 2; ++mt)
          acc[mt][j] = mfma16(a[mt], bb, acc[mt][j]);
      }
    }
  };

  issueX(xA, 0); issueW(0);
  writeXb(0, xA); writeWb(0);
  issueX(xB, 1);
  __syncthreads();

  for (int kt = 0; kt < 16; kt += 2) {
    issueW(kt + 1);
    issueX(xA, kt + 2);
    compute(0);
    if (kt + 1 < 16) { writeXb(1, xB); writeWb(1); }
    __syncthreads();
    if (kt + 1 < 16) {
      issueW(kt + 2);
      issueX(xB, kt + 3);
      compute(1);
      if (kt + 2 < 16) { writeXb(0, xA); writeWb(0); }
      __syncthreads();
    }
  }

#pragma unroll
  for (int j = 0; j < 3; ++j) {
    int ntg = wv * 3 + j;
    int mtx = ntg >> 2, nc = (ntg & 3) * 16;
    if (mtx < 2) {
      const float* bias = (mtx == 0) ? bq : bk;
      unsigned short* Out = (mtx == 0) ? Qb : Kb;
      float bvv = bias[nc + ln15] * ((mtx == 0) ? QSCALE : 1.0f);
#pragma unroll
      for (int mt = 0; mt < 2; ++mt)
#pragma unroll
        for (int i = 0; i < 4; ++i)
          Out[(m0 + mt * 16 + 4 * g + i) * 64 + nc + ln15] = f2bf(acc[mt][j][i] + bvv);
    } else {
      float bvv = bv[nc + ln15];
#pragma unroll
      for (int mt = 0; mt < 2; ++mt)
#pragma unroll
        for (int i = 0; i < 4; ++i)
          VTs[(nc + ln15) * 40 + mt * 16 + 4 * g + i] = f2bf(acc[mt][j][i] + bvv);
    }
  }
  __syncthreads();
  {
    int d = tid >> 2, t8 = (tid & 3) * 8;
    u32x4 v0 = *(const u32x4*)&VTs[d * 40 + t8];
    size_t b = m0 >> 11, tloc = m0 & 2047;
    *(u32x4*)&VTb[(b * 64 + d) * T_DIM + tloc + t8] = v0;
  }
}

// ---------------------------------------------------------------------------
// attn_flash: swapped-operand flash attention, KV-STRIP = 128 per iteration
// (8 n-frags). One softmax pass / one acc-rescale / one P LDS round-trip per
// 128 keys (vs per 64) — halves the serial per-iteration overhead that r9
// showed is the binding cost. Single dispatch, in-kernel 4-way merge (r12
// structure). K frags die before V frags load; V processed in two named
// halves. exp2-domain softmax. Grid 512 (64 qt x 8 b), LPT.
// ---------------------------------------------------------------------------
__global__ __launch_bounds__(256, 2) void attn_flash(
    const unsigned short* __restrict__ Qb,   // [B*T][64] (pre-scaled QSCALE)
    const unsigned short* __restrict__ Kb,   // [B*T][64]
    const unsigned short* __restrict__ VTb,  // [B][64][T]
    float* __restrict__ out)                 // [B*T][64] f32
{
  __shared__ __align__(16) char Usm[32768];  // union: Ps 4w x 8KB / Zs 25.5KB
  __shared__ float Ml[3][2][16][2];

  const int tid  = threadIdx.x;
  const int wv   = tid >> 6;
  const int lane = tid & 63;
  const int g    = lane >> 4;
  const int ln15 = lane & 15;

  const int qt = 63 - (blockIdx.x >> 3);     // 32-row q-tiles, longest first
  const int b  = blockIdx.x & 7;
  const int r0 = qt * 32;
  const int ntiles = (qt >> 2) + 1;          // 128-wide kv strips

  const size_t bT = (size_t)b * T_DIM;

  bf16x8 qa[2][2];
#pragma unroll
  for (int mt = 0; mt < 2; ++mt) {
    const unsigned short* qp = Qb + (bT + r0 + mt * 16 + ln15) * 64 + g * 8;
    qa[mt][0] = *(const bf16x8*)qp;
    qa[mt][1] = *(const bf16x8*)(qp + 32);
  }

  f32x4 acc[2][4];
#pragma unroll
  for (int mt = 0; mt < 2; ++mt)
#pragma unroll
    for (int dt = 0; dt < 4; ++dt) acc[mt][dt] = (f32x4){0.f, 0.f, 0.f, 0.f};
  float m_[2], l_[2];
#pragma unroll
  for (int mt = 0; mt < 2; ++mt) { m_[mt] = NEG_BIG; l_[mt] = 0.f; }

  char* myP = Usm + wv * 8192;               // per-wave 2 mt x 16 q x 256 B

  for (int it = wv; it < ntiles; it += 4) {
    const int s0 = it * 128;
    // K fragments for the whole 128-strip (die after QK^T)
    bf16x8 kf[8][2];
#pragma unroll
    for (int nt = 0; nt < 8; ++nt) {
      const unsigned short* kp = Kb + (bT + s0 + nt * 16 + ln15) * 64 + g * 8;
      kf[nt][0] = *(const bf16x8*)kp;
      kf[nt][1] = *(const bf16x8*)(kp + 32);
    }
    // S^T = K·Q^T
    f32x4 st[2][8];
#pragma unroll
    for (int mt = 0; mt < 2; ++mt)
#pragma unroll
      for (int nt = 0; nt < 8; ++nt) {
        f32x4 a = (f32x4){0.f, 0.f, 0.f, 0.f};
        a = mfma16(kf[nt][0], qa[mt][0], a);
        a = mfma16(kf[nt][1], qa[mt][1], a);
        st[mt][nt] = a;
      }
    // causal mask: kv = s0+nt*16+4g+i vs q = r0+mt*16+ln15
    if (s0 + 127 > r0) {
#pragma unroll
      for (int mt = 0; mt < 2; ++mt) {
        const int qg = r0 + mt * 16 + ln15;
#pragma unroll
        for (int nt = 0; nt < 8; ++nt) {
          const int kvb = s0 + nt * 16 + 4 * g;
#pragma unroll
          for (int i = 0; i < 4; ++i)
            if (kvb + i > qg) st[mt][nt][i] = NEG_BIG;
        }
      }
    }
    // ONE softmax pass per mt over all 128 kv
#pragma unroll
    for (int mt = 0; mt < 2; ++mt) {
      f32x4 t4 = st[mt][0];
#pragma unroll
      for (int nt = 1; nt < 8; ++nt)
#pragma unroll
        for (int i = 0; i < 4; ++i) t4[i] = fmaxf(t4[i], st[mt][nt][i]);
      float mx = fmaxf(fmaxf(t4[0], t4[1]), fmaxf(t4[2], t4[3]));
      mx = fmaxf(mx, __shfl_xor(mx, 16));
      mx = fmaxf(mx, __shfl_xor(mx, 32));
      const float mn = fmaxf(m_[mt], mx);
      const float corr = exp2f(m_[mt] - mn);
      m_[mt] = mn;
#pragma unroll
      for (int nt = 0; nt < 8; ++nt)
#pragma unroll
        for (int i = 0; i < 4; ++i)
          st[mt][nt][i] = exp2f(st[mt][nt][i] - mn);
      float ps = 0.f;
#pragma unroll
      for (int nt = 0; nt < 8; ++nt)
        ps += (st[mt][nt][0] + st[mt][nt][1]) + (st[mt][nt][2] + st[mt][nt][3]);
      ps += __shfl_xor(ps, 16);
      ps += __shfl_xor(ps, 32);
      l_[mt] = l_[mt] * corr + ps;
#pragma unroll
      for (int dt = 0; dt < 4; ++dt)
#pragma unroll
        for (int i = 0; i < 4; ++i)
          acc[mt][dt][i] *= corr;
      // P^T pack: one b64 per nt (row q=ln15, stride 256 B)
#pragma unroll
      for (int nt = 0; nt < 8; ++nt) {
        unsigned int lo_ = (unsigned int)f2bf(st[mt][nt][0]) | ((unsigned int)f2bf(st[mt][nt][1]) << 16);
        unsigned int hi_ = (unsigned int)f2bf(st[mt][nt][2]) | ((unsigned int)f2bf(st[mt][nt][3]) << 16);
        *(unsigned long long*)(myP + mt * 4096 + ln15 * 256 +
                               ((nt * 32 + g * 8) ^ ((ln15 & 7) << 4))) =
            ((unsigned long long)hi_ << 32) | lo_;
      }
    }
    // P^T B-operand reads (4 kc per mt) + PV in two V-halves (named regs)
    bf16x8 pb[2][4];
#pragma unroll
    for (int mt = 0; mt < 2; ++mt)
#pragma unroll
      for (int kc = 0; kc < 4; ++kc)
        pb[mt][kc] = *(const bf16x8*)(myP + mt * 4096 + ln15 * 256 +
                                      ((kc * 64 + g * 16) ^ ((ln15 & 7) << 4)));
    {
      bf16x8 vfA[4][2];
#pragma unroll
      for (int dt = 0; dt < 4; ++dt) {
        const unsigned short* vp = VTb + ((size_t)b * 64 + dt * 16 + ln15) * T_DIM + s0 + g * 8;
        vfA[dt][0] = *(const bf16x8*)vp;
        vfA[dt][1] = *(const bf16x8*)(vp + 32);
      }
#pragma unroll
      for (int mt = 0; mt < 2; ++mt)
#pragma unroll
        for (int dt = 0; dt < 4; ++dt) {
          acc[mt][dt] = mfma16(vfA[dt][0], pb[mt][0], acc[mt][dt]);
          acc[mt][dt] = mfma16(vfA[dt][1], pb[mt][1], acc[mt][dt]);
        }
      bf16x8 vfB[4][2];
#pragma unroll
      for (int dt = 0; dt < 4; ++dt) {
        const unsigned short* vp = VTb + ((size_t)b * 64 + dt * 16 + ln15) * T_DIM + s0 + 64 + g * 8;
        vfB[dt][0] = *(const bf16x8*)vp;
        vfB[dt][1] = *(const bf16x8*)(vp + 32);
      }
#pragma unroll
      for (int mt = 0; mt < 2; ++mt)
#pragma unroll
        for (int dt = 0; dt < 4; ++dt) {
          acc[mt][dt] = mfma16(vfB[dt][0], pb[mt][2], acc[mt][dt]);
          acc[mt][dt] = mfma16(vfB[dt][1], pb[mt][3], acc[mt][dt]);
        }
    }
  }

  // 4-way merge (Ps dead; reuse union as Zs)
  __syncthreads();
  float* Zsf = (float*)Usm;                  // [3][2][16*68]
  if (wv > 0) {
#pragma unroll
    for (int mt = 0; mt < 2; ++mt) {
#pragma unroll
      for (int dt = 0; dt < 4; ++dt)
        *(f32x4*)&Zsf[((wv - 1) * 2 + mt) * 1088 + ln15 * 68 + dt * 16 + 4 * g] = acc[mt][dt];
      if (g == 0) {
        Ml[wv - 1][mt][ln15][0] = m_[mt];
        Ml[wv - 1][mt][ln15][1] = l_[mt];
      }
    }
  }
  __syncthreads();
  if (wv == 0) {
#pragma unroll
    for (int mt = 0; mt < 2; ++mt) {
      float mm = m_[mt];
#pragma unroll
      for (int w = 0; w < 3; ++w) mm = fmaxf(mm, Ml[w][mt][ln15][0]);
      const float e0 = exp2f(m_[mt] - mm);
      float lsum = l_[mt] * e0;
      float ew[3];
#pragma unroll
      for (int w = 0; w < 3; ++w) {
        ew[w] = exp2f(Ml[w][mt][ln15][0] - mm);
        lsum += Ml[w][mt][ln15][1] * ew[w];
      }
      const float inv = 1.0f / lsum;
      float* ob = out + (bT + r0 + mt * 16 + ln15) * 64;
#pragma unroll
      for (int dt = 0; dt < 4; ++dt) {
        f32x4 z;
#pragma unroll
        for (int i = 0; i < 4; ++i) {
          float zz = acc[mt][dt][i] * e0;
#pragma unroll
          for (int w = 0; w < 3; ++w)
            zz += Zsf[(w * 2 + mt) * 1088 + ln15 * 68 + dt * 16 + 4 * g + i] * ew[w];
          z[i] = zz * inv;
        }
        *(f32x4*)&ob[dt * 16 + 4 * g] = z;
      }
    }
  }
}

// ---------------------------------------------------------------------------
extern "C" void kernel_launch(void* const* d_in, const int* in_sizes, int n_in,
                              void* d_out, int out_size, void* d_ws, size_t ws_size,
                              hipStream_t stream)
{
  const float* x  = (const float*)d_in[0];
  const float* Wq = (const float*)d_in[1];
  const float* bq = (const float*)d_in[2];
  const float* Wk = (const float*)d_in[3];
  const float* bk = (const float*)d_in[4];
  const float* Wv = (const float*)d_in[5];
  const float* bv = (const float*)d_in[6];
  float* out = (float*)d_out;

  char* ws = (char*)d_ws;
  unsigned short* Wt  = (unsigned short*)(ws);                      // 384 KB
  unsigned short* Qb  = (unsigned short*)(ws + (1u << 19));         // 2 MB
  unsigned short* Kb  = (unsigned short*)(ws + (1u << 19) + (1u << 21));
  unsigned short* VTb = (unsigned short*)(ws + (1u << 19) + (2u << 21));

  prep_w<<<48, 256, 0, stream>>>(Wq, Wk, Wv, Wt);
  qkv_proj_mfma<<<512, 256, 0, stream>>>(x, Wt, bq, bk, bv, Qb, Kb, VTb);
  attn_flash<<<512, 256, 0, stream>>>(Qb, Kb, VTb, out);
}

// Round 15
// 53.001 us; speedup vs baseline: 1.0828x; 1.0358x over previous
//
#include <hip/hip_runtime.h>
#include <hip/hip_bf16.h>
#include <cstdint>
#include <cstddef>

typedef __attribute__((ext_vector_type(8))) short bf16x8;
typedef __attribute__((ext_vector_type(4))) float f32x4;
typedef __attribute__((ext_vector_type(4))) unsigned int u32x4;

#define T_DIM 2048
#define C_DIM 1024
#define B_DIM 8
#define NEG_BIG (-3.0e38f)
#define QSCALE 0.18033688011112042f   // (1/8) * log2(e): softmax in exp2 domain

__device__ __forceinline__ unsigned short f2bf(float f) {
  union { __hip_bfloat16 h; unsigned short u; } cv;
  cv.h = __float2bfloat16(f);
  return cv.u;
}
__device__ __forceinline__ f32x4 mfma16(bf16x8 a, bf16x8 b, f32x4 c) {
  return __builtin_amdgcn_mfma_f32_16x16x32_bf16(a, b, c, 0, 0, 0);
}

// ---------------------------------------------------------------------------
// prep_w: W [1024][64] f32 -> Wt [3][64][1024] bf16 (transposed; Wq scaled by
// (1/8)*log2e so softmax runs in exp2 domain). Unchanged.
// ---------------------------------------------------------------------------
__global__ __launch_bounds__(256) void prep_w(
    const float* __restrict__ Wq, const float* __restrict__ Wk,
    const float* __restrict__ Wv, unsigned short* __restrict__ Wt)
{
  const int mtx = blockIdx.x >> 4;
  const int k0  = (blockIdx.x & 15) * 64;
  const float* W = (mtx == 0) ? Wq : ((mtx == 1) ? Wk : Wv);
  const float scale = (mtx == 0) ? QSCALE : 1.0f;
  __shared__ float Ws[64][65];
  const int t = threadIdx.x;
#pragma unroll
  for (int j = 0; j < 4; ++j) {
    int r = (t >> 4) + 16 * j;
    int c = (t & 15) * 4;
    union { float4 f4; float f[4]; } uv;
    uv.f4 = *(const float4*)&W[(size_t)(k0 + r) * 64 + c];
#pragma unroll
    for (int jj = 0; jj < 4; ++jj) Ws[c + jj][r] = uv.f[jj] * scale;
  }
  __syncthreads();
#pragma unroll
  for (int q = 0; q < 2; ++q) {
    int g_ = t + 256 * q;
    int d  = g_ >> 3;
    int ko = (g_ & 7) * 8;
    union { unsigned short u[8]; u32x4 v; } pk;
#pragma unroll
    for (int jj = 0; jj < 8; ++jj) pk.u[jj] = f2bf(Ws[d][ko + jj]);
    *(u32x4*)&Wt[((size_t)mtx * 64 + d) * C_DIM + k0 + ko] = pk.v;
  }
}

// ---------------------------------------------------------------------------
// qkv_proj_mfma: round-12 pipelined version (512 x 32 rows). Unchanged.
// ---------------------------------------------------------------------------
__global__ __launch_bounds__(256) void qkv_proj_mfma(
    const float* __restrict__ x,
    const unsigned short* __restrict__ Wt,
    const float* __restrict__ bq, const float* __restrict__ bk, const float* __restrict__ bv,
    unsigned short* __restrict__ Qb, unsigned short* __restrict__ Kb,
    unsigned short* __restrict__ VTb)
{
  __shared__ __align__(16) short Xs[2][32 * 64];
  __shared__ __align__(16) short Wsb[2][3 * 64 * 64];
  __shared__ __align__(16) unsigned short VTs[64 * 40];

  const int tid = threadIdx.x;
  const int wv = tid >> 6, lane = tid & 63, g = lane >> 4, ln15 = lane & 15;
  const size_t m0 = (size_t)blockIdx.x * 32;

  f32x4 acc[2][3];
#pragma unroll
  for (int mt = 0; mt < 2; ++mt)
#pragma unroll
    for (int j = 0; j < 3; ++j) acc[mt][j] = (f32x4){0.f, 0.f, 0.f, 0.f};

  float4 xA[2], xB[2];
  u32x4 wr[6];

  auto issueX = [&](float4 (&xr)[2], int kt) {
    if (kt >= 16) return;
#pragma unroll
    for (int q = 0; q < 2; ++q) {
      int g_ = tid + 256 * q;
      int r = g_ >> 4, c4 = (g_ & 15) * 4;
      xr[q] = *(const float4*)&x[(m0 + r) * C_DIM + kt * 64 + c4];
    }
  };
  auto issueW = [&](int kt) {
    if (kt >= 16) return;
#pragma unroll
    for (int mt = 0; mt < 3; ++mt)
#pragma unroll
      for (int q = 0; q < 2; ++q) {
        int g_ = tid + 256 * q;
        int d = g_ >> 3, ko = (g_ & 7) * 8;
        wr[mt * 2 + q] = *(const u32x4*)&Wt[((size_t)mt * 64 + d) * C_DIM + kt * 64 + ko];
      }
  };
  auto writeXb = [&](int nb, const float4 (&xr)[2]) {
#pragma unroll
    for (int q = 0; q < 2; ++q) {
      int g_ = tid + 256 * q;
      int r = g_ >> 4, c4 = (g_ & 15) * 4;
      const float* f = (const float*)&xr[q];
      union { unsigned short u[4]; unsigned long long ll; } pk;
#pragma unroll
      for (int jj = 0; jj < 4; ++jj) pk.u[jj] = f2bf(f[jj]);
      *(unsigned long long*)((char*)Xs[nb] + r * 128 + ((c4 * 2) ^ ((r & 7) << 4))) = pk.ll;
    }
  };
  auto writeWb = [&](int nb) {
#pragma unroll
    for (int mt = 0; mt < 3; ++mt)
#pragma unroll
      for (int q = 0; q < 2; ++q) {
        int g_ = tid + 256 * q;
        int d = g_ >> 3, ko = (g_ & 7) * 8;
        *(u32x4*)((char*)Wsb[nb] + mt * 8192 + d * 128 + ((ko * 2) ^ ((d & 7) << 4))) = wr[mt * 2 + q];
      }
  };
  auto compute = [&](int nb) {
#pragma unroll
    for (int kc = 0; kc < 2; ++kc) {
      bf16x8 a[2];
#pragma unroll
      for (int mt = 0; mt < 2; ++mt) {
        int xr = mt * 16 + ln15;
        a[mt] = *(const bf16x8*)((const char*)Xs[nb] + xr * 128 + ((kc * 64 + g * 16) ^ ((xr & 7) << 4)));
      }
#pragma unroll
      for (int j = 0; j < 3; ++j) {
        int ntg = wv * 3 + j;
        int mtx = ntg >> 2, nc = (ntg & 3) * 16;
        int wrow = nc + ln15;
        bf16x8 bb = *(const bf16x8*)((const char*)Wsb[nb] + mtx * 8192 + wrow * 128 + ((kc * 64 + g * 16) ^ ((wrow & 7) << 4)));
#pragma unroll
        for (int mt = 0; mt < 2; ++mt)
          acc[mt][j] = mfma16(a[mt], bb, acc[mt][j]);
      }
    }
  };

  issueX(xA, 0); issueW(0);
  writeXb(0, xA); writeWb(0);
  issueX(xB, 1);
  __syncthreads();

  for (int kt = 0; kt < 16; kt += 2) {
    issueW(kt + 1);
    issueX(xA, kt + 2);
    compute(0);
    if (kt + 1 < 16) { writeXb(1, xB); writeWb(1); }
    __syncthreads();
    if (kt + 1 < 16) {
      issueW(kt + 2);
      issueX(xB, kt + 3);
      compute(1);
      if (kt + 2 < 16) { writeXb(0, xA); writeWb(0); }
      __syncthreads();
    }
  }

#pragma unroll
  for (int j = 0; j < 3; ++j) {
    int ntg = wv * 3 + j;
    int mtx = ntg >> 2, nc = (ntg & 3) * 16;
    if (mtx < 2) {
      const float* bias = (mtx == 0) ? bq : bk;
      unsigned short* Out = (mtx == 0) ? Qb : Kb;
      float bvv = bias[nc + ln15] * ((mtx == 0) ? QSCALE : 1.0f);
#pragma unroll
      for (int mt = 0; mt < 2; ++mt)
#pragma unroll
        for (int i = 0; i < 4; ++i)
          Out[(m0 + mt * 16 + 4 * g + i) * 64 + nc + ln15] = f2bf(acc[mt][j][i] + bvv);
    } else {
      float bvv = bv[nc + ln15];
#pragma unroll
      for (int mt = 0; mt < 2; ++mt)
#pragma unroll
        for (int i = 0; i < 4; ++i)
          VTs[(nc + ln15) * 40 + mt * 16 + 4 * g + i] = f2bf(acc[mt][j][i] + bvv);
    }
  }
  __syncthreads();
  {
    int d = tid >> 2, t8 = (tid & 3) * 8;
    u32x4 v0 = *(const u32x4*)&VTs[d * 40 + t8];
    size_t b = m0 >> 11, tloc = m0 & 2047;
    *(u32x4*)&VTb[(b * 64 + d) * T_DIM + tloc + t8] = v0;
  }
}

// ---------------------------------------------------------------------------
// attn_flash: r12 structure (KV=64, swapped-operand, in-kernel 4-way merge)
// + three chain cuts:
//   (1) l-sum deferred: per-lane partial, ONE cross-lane reduce at the end
//       (l is linear under the uniform corr sequence).
//   (2) defer-max THR=8 (exp2 domain): per-lane check, wave-__all; skip
//       max-shfls / corr / m-update / acc-rescale when no significant growth.
//   (3) s_setprio(1) around MFMA clusters.
// ---------------------------------------------------------------------------
__global__ __launch_bounds__(256, 2) void attn_flash(
    const unsigned short* __restrict__ Qb,   // [B*T][64] (pre-scaled QSCALE)
    const unsigned short* __restrict__ Kb,   // [B*T][64]
    const unsigned short* __restrict__ VTb,  // [B][64][T]
    float* __restrict__ out)                 // [B*T][64] f32
{
  __shared__ __align__(16) short Ps[4][2 * 16 * 64];
  __shared__ __align__(16) float Zs[3][2][16 * 68];
  __shared__ float Ml[3][2][16][2];

  const int tid  = threadIdx.x;
  const int wv   = tid >> 6;
  const int lane = tid & 63;
  const int g    = lane >> 4;
  const int ln15 = lane & 15;

  const int qt = 63 - (blockIdx.x >> 3);
  const int b  = blockIdx.x & 7;
  const int r0 = qt * 32;
  const int ntiles = (qt >> 1) + 1;

  const size_t bT = (size_t)b * T_DIM;

  bf16x8 qa[2][2];
#pragma unroll
  for (int mt = 0; mt < 2; ++mt) {
    const unsigned short* qp = Qb + (bT + r0 + mt * 16 + ln15) * 64 + g * 8;
    qa[mt][0] = *(const bf16x8*)qp;
    qa[mt][1] = *(const bf16x8*)(qp + 32);
  }

  f32x4 acc[2][4];
#pragma unroll
  for (int mt = 0; mt < 2; ++mt)
#pragma unroll
    for (int dt = 0; dt < 4; ++dt) acc[mt][dt] = (f32x4){0.f, 0.f, 0.f, 0.f};
  float m_[2], l_[2];
#pragma unroll
  for (int mt = 0; mt < 2; ++mt) { m_[mt] = NEG_BIG; l_[mt] = 0.f; }

  char* myP = (char*)Ps[wv];

  for (int it = wv; it < ntiles; it += 4) {
    const int s0 = it * 64;
    bf16x8 kf[4][2];
#pragma unroll
    for (int nt = 0; nt < 4; ++nt) {
      const unsigned short* kp = Kb + (bT + s0 + nt * 16 + ln15) * 64 + g * 8;
      kf[nt][0] = *(const bf16x8*)kp;
      kf[nt][1] = *(const bf16x8*)(kp + 32);
    }
    bf16x8 vf[4][2];
#pragma unroll
    for (int dt = 0; dt < 4; ++dt) {
      const unsigned short* vp = VTb + ((size_t)b * 64 + dt * 16 + ln15) * T_DIM + s0 + g * 8;
      vf[dt][0] = *(const bf16x8*)vp;
      vf[dt][1] = *(const bf16x8*)(vp + 32);
    }
    f32x4 st[2][4];
    __builtin_amdgcn_s_setprio(1);
#pragma unroll
    for (int mt = 0; mt < 2; ++mt)
#pragma unroll
      for (int nt = 0; nt < 4; ++nt) {
        f32x4 a = (f32x4){0.f, 0.f, 0.f, 0.f};
        a = mfma16(kf[nt][0], qa[mt][0], a);
        a = mfma16(kf[nt][1], qa[mt][1], a);
        st[mt][nt] = a;
      }
    __builtin_amdgcn_s_setprio(0);
    if (s0 + 63 > r0) {
#pragma unroll
      for (int mt = 0; mt < 2; ++mt) {
        const int qg = r0 + mt * 16 + ln15;
#pragma unroll
        for (int nt = 0; nt < 4; ++nt) {
          const int kvb = s0 + nt * 16 + 4 * g;
#pragma unroll
          for (int i = 0; i < 4; ++i)
            if (kvb + i > qg) st[mt][nt][i] = NEG_BIG;
        }
      }
    }
#pragma unroll
    for (int mt = 0; mt < 2; ++mt) {
      // per-lane strip max (15 fmax, no shfl yet)
      f32x4 t4;
#pragma unroll
      for (int i = 0; i < 4; ++i)
        t4[i] = fmaxf(fmaxf(st[mt][0][i], st[mt][1][i]), fmaxf(st[mt][2][i], st[mt][3][i]));
      float mx = fmaxf(fmaxf(t4[0], t4[1]), fmaxf(t4[2], t4[3]));
      // defer-max: skip rescale when no lane grew past m+8 (P bounded by 2^8)
      if (!__all((int)(mx <= m_[mt] + 8.0f))) {
        mx = fmaxf(mx, __shfl_xor(mx, 16));
        mx = fmaxf(mx, __shfl_xor(mx, 32));
        const float mn = fmaxf(m_[mt], mx);
        const float corr = exp2f(m_[mt] - mn);
        m_[mt] = mn;
        l_[mt] *= corr;
#pragma unroll
        for (int dt = 0; dt < 4; ++dt)
#pragma unroll
          for (int i = 0; i < 4; ++i)
            acc[mt][dt][i] *= corr;
      }
#pragma unroll
      for (int nt = 0; nt < 4; ++nt)
#pragma unroll
        for (int i = 0; i < 4; ++i)
          st[mt][nt][i] = exp2f(st[mt][nt][i] - m_[mt]);
      // per-lane partial l (cross-lane reduce deferred to the end)
      float ps = 0.f;
#pragma unroll
      for (int nt = 0; nt < 4; ++nt)
        ps += (st[mt][nt][0] + st[mt][nt][1]) + (st[mt][nt][2] + st[mt][nt][3]);
      l_[mt] += ps;
#pragma unroll
      for (int nt = 0; nt < 4; ++nt) {
        unsigned int lo_ = (unsigned int)f2bf(st[mt][nt][0]) | ((unsigned int)f2bf(st[mt][nt][1]) << 16);
        unsigned int hi_ = (unsigned int)f2bf(st[mt][nt][2]) | ((unsigned int)f2bf(st[mt][nt][3]) << 16);
        *(unsigned long long*)(myP + mt * 2048 + ln15 * 128 +
                               ((nt * 32 + g * 8) ^ ((ln15 & 7) << 4))) =
            ((unsigned long long)hi_ << 32) | lo_;
      }
    }
    bf16x8 pb[2][2];
#pragma unroll
    for (int mt = 0; mt < 2; ++mt)
#pragma unroll
      for (int kc = 0; kc < 2; ++kc)
        pb[mt][kc] = *(const bf16x8*)(myP + mt * 2048 + ln15 * 128 +
                                      ((kc * 64 + g * 16) ^ ((ln15 & 7) << 4)));
    __builtin_amdgcn_s_setprio(1);
#pragma unroll
    for (int mt = 0; mt < 2; ++mt)
#pragma unroll
      for (int dt = 0; dt < 4; ++dt) {
        acc[mt][dt] = mfma16(vf[dt][0], pb[mt][0], acc[mt][dt]);
        acc[mt][dt] = mfma16(vf[dt][1], pb[mt][1], acc[mt][dt]);
      }
    __builtin_amdgcn_s_setprio(0);
  }

  // finalize deferred l: one cross-lane reduce per mt
#pragma unroll
  for (int mt = 0; mt < 2; ++mt) {
    l_[mt] += __shfl_xor(l_[mt], 16);
    l_[mt] += __shfl_xor(l_[mt], 32);
  }

  if (wv > 0) {
#pragma unroll
    for (int mt = 0; mt < 2; ++mt) {
#pragma unroll
      for (int dt = 0; dt < 4; ++dt)
        *(f32x4*)&Zs[wv - 1][mt][ln15 * 68 + dt * 16 + 4 * g] = acc[mt][dt];
      if (g == 0) {
        Ml[wv - 1][mt][ln15][0] = m_[mt];
        Ml[wv - 1][mt][ln15][1] = l_[mt];
      }
    }
  }
  __syncthreads();
  if (wv == 0) {
#pragma unroll
    for (int mt = 0; mt < 2; ++mt) {
      float mm = m_[mt];
#pragma unroll
      for (int w = 0; w < 3; ++w) mm = fmaxf(mm, Ml[w][mt][ln15][0]);
      const float e0 = exp2f(m_[mt] - mm);
      float lsum = l_[mt] * e0;
      float ew[3];
#pragma unroll
      for (int w = 0; w < 3; ++w) {
        ew[w] = exp2f(Ml[w][mt][ln15][0] - mm);
        lsum += Ml[w][mt][ln15][1] * ew[w];
      }
      const float inv = 1.0f / lsum;
      float* ob = out + (bT + r0 + mt * 16 + ln15) * 64;
#pragma unroll
      for (int dt = 0; dt < 4; ++dt) {
        f32x4 z;
#pragma unroll
        for (int i = 0; i < 4; ++i) {
          float zz = acc[mt][dt][i] * e0;
#pragma unroll
          for (int w = 0; w < 3; ++w)
            zz += Zs[w][mt][ln15 * 68 + dt * 16 + 4 * g + i] * ew[w];
          z[i] = zz * inv;
        }
        *(f32x4*)&ob[dt * 16 + 4 * g] = z;
      }
    }
  }
}

// ---------------------------------------------------------------------------
extern "C" void kernel_launch(void* const* d_in, const int* in_sizes, int n_in,
                              void* d_out, int out_size, void* d_ws, size_t ws_size,
                              hipStream_t stream)
{
  const float* x  = (const float*)d_in[0];
  const float* Wq = (const float*)d_in[1];
  const float* bq = (const float*)d_in[2];
  const float* Wk = (const float*)d_in[3];
  const float* bk = (const float*)d_in[4];
  const float* Wv = (const float*)d_in[5];
  const float* bv = (const float*)d_in[6];
  float* out = (float*)d_out;

  char* ws = (char*)d_ws;
  unsigned short* Wt  = (unsigned short*)(ws);                      // 384 KB
  unsigned short* Qb  = (unsigned short*)(ws + (1u << 19));         // 2 MB
  unsigned short* Kb  = (unsigned short*)(ws + (1u << 19) + (1u << 21));
  unsigned short* VTb = (unsigned short*)(ws + (1u << 19) + (2u << 21));

  prep_w<<<48, 256, 0, stream>>>(Wq, Wk, Wv, Wt);
  qkv_proj_mfma<<<512, 256, 0, stream>>>(x, Wt, bq, bk, bv, Qb, Kb, VTb);
  attn_flash<<<512, 256, 0, stream>>>(Qb, Kb, VTb, out);
}